// Round 6
// baseline (108.883 us; speedup 1.0000x reference)
//
#include <hip/hip_runtime.h>
#include <stdint.h>

#define HEADS 12
#define DMODEL 768
#define BATCH 2
#define SEQ 2048
#define BS (BATCH * SEQ)
#define HD 64

typedef float f32x4 __attribute__((ext_vector_type(4)));
typedef __bf16 bf16x8 __attribute__((ext_vector_type(8)));
typedef unsigned short u16;
typedef u16 u16x8 __attribute__((ext_vector_type(8)));
typedef u16 u16x4 __attribute__((ext_vector_type(4)));

__device__ __forceinline__ u16 f2b(float f) {
    return __builtin_bit_cast(u16, (__bf16)f);
}

__device__ __forceinline__ void gld_lds16(const void* g, void* l) {
    __builtin_amdgcn_global_load_lds(
        (__attribute__((address_space(1))) void*)(g),
        (__attribute__((address_space(3))) void*)(l), 16, 0, 0);
}

// ---------------- prep: fp32 -> bf16 (vectorized) ----------------
__global__ __launch_bounds__(256) void cvt_x(
    const float* __restrict__ q, const float* __restrict__ k, const float* __restrict__ v,
    u16* __restrict__ xq, u16* __restrict__ xk, u16* __restrict__ xv) {
    int z = blockIdx.z;
    const float* s = (z == 0) ? q : (z == 1) ? k : v;
    u16* d = (z == 0) ? xq : (z == 1) ? xk : xv;
    size_t i = (size_t)blockIdx.x * blockDim.x + threadIdx.x;
    const float4* s4 = (const float4*)s;
    float4 a = s4[2 * i], b = s4[2 * i + 1];
    u16x8 o;
    o[0] = f2b(a.x); o[1] = f2b(a.y); o[2] = f2b(a.z); o[3] = f2b(a.w);
    o[4] = f2b(b.x); o[5] = f2b(b.y); o[6] = f2b(b.z); o[7] = f2b(b.w);
    *(u16x8*)(d + 8 * i) = o;
}

// ---------------- prep: W -> W^T bf16 ----------------
__global__ void cvt_wt(const float* __restrict__ wq, const float* __restrict__ wk,
                       const float* __restrict__ wv,
                       u16* __restrict__ tq, u16* __restrict__ tk, u16* __restrict__ tv) {
    int z = blockIdx.z;
    const float* w = (z == 0) ? wq : (z == 1) ? wk : wv;
    u16* t = (z == 0) ? tq : (z == 1) ? tk : tv;
    __shared__ float tile[32][33];
    int tx = threadIdx.x, ty = threadIdx.y;
    int kb = blockIdx.y * 32, nb = blockIdx.x * 32;
    for (int r = 0; r < 32; r += 8)
        tile[ty + r][tx] = w[(size_t)(kb + ty + r) * DMODEL + nb + tx];
    __syncthreads();
    for (int r = 0; r < 32; r += 8)
        t[(size_t)(nb + ty + r) * DMODEL + kb + tx] = f2b(tile[tx][ty + r]);
}

// ---------------- projection GEMM: C[m][n] = X[m][k] * W[k][n] ----------------
// z=0 -> qw [B,H,S,64] PRE-SCALED by 0.125*log2(e); z=1 -> kw [B,H,S,64];
// z=2 -> vt [B,H,64,S] (V stored transposed for attention)
__global__ __launch_bounds__(256, 2) void proj_gemm(
    const u16* __restrict__ xq, const u16* __restrict__ xk, const u16* __restrict__ xv,
    const u16* __restrict__ tq, const u16* __restrict__ tk, const u16* __restrict__ tv,
    u16* __restrict__ oq, u16* __restrict__ ok, u16* __restrict__ ov) {
    const int z = blockIdx.z;
    const u16* X  = (z == 0) ? xq : (z == 1) ? xk : xv;
    const u16* WT = (z == 0) ? tq : (z == 1) ? tk : tv;
    u16* Out      = (z == 0) ? oq : (z == 1) ? ok : ov;

    __shared__ u16 As[128 * 64];
    __shared__ u16 Bs[128 * 64];

    const int tid = threadIdx.x;
    const int lane = tid & 63, w = tid >> 6;
    const int wm = w >> 1, wn = w & 1;
    const int m0 = blockIdx.x * 128, n0 = blockIdx.y * 128;

    f32x4 acc[4][4] = {};

    for (int kt = 0; kt < DMODEL / 64; ++kt) {
#pragma unroll
        for (int p = 0; p < 4; ++p) {
            int o = (p * 4 + w) * 1024 + lane * 16;
            int row = o >> 7;
            int col = (o & 127) ^ ((row & 7) << 4);
            gld_lds16((const char*)X + (size_t)(m0 + row) * (DMODEL * 2) + kt * 128 + col,
                      (char*)As + (p * 4 + w) * 1024);
            gld_lds16((const char*)WT + (size_t)(n0 + row) * (DMODEL * 2) + kt * 128 + col,
                      (char*)Bs + (p * 4 + w) * 1024);
        }
        __syncthreads();
#pragma unroll
        for (int kk = 0; kk < 2; ++kk) {
            bf16x8 af[4], bfr[4];
#pragma unroll
            for (int mi = 0; mi < 4; ++mi) {
                int row = wm * 64 + mi * 16 + (lane & 15);
                int col = (kk * 64 + ((lane >> 4) << 4)) ^ ((row & 7) << 4);
                af[mi] = *(const bf16x8*)((const char*)As + row * 128 + col);
            }
#pragma unroll
            for (int ni = 0; ni < 4; ++ni) {
                int row = wn * 64 + ni * 16 + (lane & 15);
                int col = (kk * 64 + ((lane >> 4) << 4)) ^ ((row & 7) << 4);
                bfr[ni] = *(const bf16x8*)((const char*)Bs + row * 128 + col);
            }
#pragma unroll
            for (int mi = 0; mi < 4; ++mi)
#pragma unroll
                for (int ni = 0; ni < 4; ++ni)
                    acc[mi][ni] = __builtin_amdgcn_mfma_f32_16x16x32_bf16(
                        af[mi], bfr[ni], acc[mi][ni], 0, 0, 0);
        }
        __syncthreads();
    }

    const float mul = (z == 0) ? 0.125f * 1.44269504f : 1.0f;
#pragma unroll
    for (int mi = 0; mi < 4; ++mi) {
        int mb = m0 + wm * 64 + mi * 16 + ((lane >> 4) << 2);
#pragma unroll
        for (int ni = 0; ni < 4; ++ni) {
            int n = n0 + wn * 64 + ni * 16 + (lane & 15);
            int h = n >> 6, dd = n & 63;
#pragma unroll
            for (int r = 0; r < 4; ++r) {
                int m = mb + r;
                int b = m >> 11, s = m & 2047;
                u16 val = f2b(acc[mi][ni][r] * mul);
                size_t off = (z == 2)
                    ? ((size_t)(b * HEADS + h) * HD + dd) * SEQ + s
                    : ((size_t)(b * HEADS + h) * SEQ + s) * HD + dd;
                Out[off] = val;
            }
        }
    }
}

// ---------------- fused attention ----------------
// 2 waves x 32 q-rows = 64 q/block (grid 32x24 = 768 blocks = 3/CU).
// Halves K/V LDS read amplification vs 4-wave version; 32 MFMA per wave-tile.
// qw: [B,H,S,64] bf16 pre-scaled by 0.125*log2e; kw: [B,H,S,64]; vt: [B,H,64,S]
__global__ __launch_bounds__(128, 2) void attn(
    const u16* __restrict__ qw, const u16* __restrict__ kw, const u16* __restrict__ vt,
    const float* __restrict__ v_mask, const float* __restrict__ q_mask,
    float* __restrict__ out) {
    __shared__ u16 Ks[2][64 * 64];   // [key][d] swizzled, double-buffered
    __shared__ u16 Vs[2][64 * 64];   // [d][key] swizzled (V^T)
    __shared__ u16 Ps[2][32 * 64];   // per-wave P^T [q(32)][key], XOR-swizzled

    const int tid = threadIdx.x;
    const int lane = tid & 63, w = tid >> 6;
    const int l15 = lane & 15, g = lane >> 4;
    const int bh = blockIdx.y;
    const int b = bh / HEADS, h = bh % HEADS;
    const int q0 = blockIdx.x * 64 + w * 32;

    const u16* qb = qw + (size_t)bh * SEQ * HD;
    const u16* kb = kw + (size_t)bh * SEQ * HD;
    const u16* vb = vt + (size_t)bh * HD * SEQ;
    const float* vmaskb = v_mask + (size_t)b * SEQ;

    // hoist Q fragments (B-operand layout: col=lane&15, k=8*(lane>>4)+j + 32*kk)
    bf16x8 qf[2][2];
#pragma unroll
    for (int qt = 0; qt < 2; ++qt)
#pragma unroll
        for (int kk = 0; kk < 2; ++kk) {
            int row = q0 + qt * 16 + l15;
            qf[qt][kk] = *(const bf16x8*)((const char*)qb + (size_t)row * 128 + kk * 64 + (g << 4));
        }

    f32x4 accO[2][4] = {};          // O^T: accO[qt][dt][r] = O[q][d=dt*16+g*4+r]
    float mrow[2] = {-1e30f, -1e30f};
    float lpart[2] = {0.f, 0.f};

    auto stage = [&](int t, int p) {
        const int kv0 = t * 64;
#pragma unroll
        for (int i = 0; i < 4; ++i) {
            int base = i * 2048 + w * 1024;       // wave-uniform LDS base
            int o = base + lane * 16;             // per-lane global offset
            int row = o >> 7;
            int col = (o & 127) ^ ((row & 7) << 4);
            gld_lds16((const char*)kb + (size_t)(kv0 + row) * 128 + col,
                      (char*)Ks[p] + base);
            gld_lds16((const char*)vb + (size_t)row * (SEQ * 2) + (size_t)kv0 * 2 + col,
                      (char*)Vs[p] + base);
        }
    };

    stage(0, 0);
    __syncthreads();

    for (int t = 0; t < SEQ / 64; ++t) {
        const int cur = t & 1;
        const int kv0 = t * 64;

        // bias prefetch into registers (v_mask is L1-resident; broadcast across l15)
        f32x4 vm[4];
#pragma unroll
        for (int kt = 0; kt < 4; ++kt)
            vm[kt] = *(const f32x4*)(vmaskb + kv0 + kt * 16 + g * 4);

        if (t + 1 < SEQ / 64) stage(t + 1, cur ^ 1);

        // ---- S^T = K Q^T (16 MFMA): sc[qt][kt][r] = S[key=kt*16+g*4+r][q=qt*16+l15]
        f32x4 sc[2][4] = {};
#pragma unroll
        for (int kk = 0; kk < 2; ++kk) {
            bf16x8 kf[4];
#pragma unroll
            for (int kt = 0; kt < 4; ++kt) {
                int row = kt * 16 + l15;
                int colB = (kk * 64 + (g << 4)) ^ ((row & 7) << 4);
                kf[kt] = *(const bf16x8*)((const char*)Ks[cur] + row * 128 + colB);
            }
            __builtin_amdgcn_s_setprio(1);
#pragma unroll
            for (int qt = 0; qt < 2; ++qt)
#pragma unroll
                for (int kt = 0; kt < 4; ++kt)
                    sc[qt][kt] = __builtin_amdgcn_mfma_f32_16x16x32_bf16(
                        kf[kt], qf[qt][kk], sc[qt][kt], 0, 0, 0);
            __builtin_amdgcn_s_setprio(0);
        }

        // ---- hoist all V fragments (latency hides under softmax VALU)
        bf16x8 vf[2][4];
#pragma unroll
        for (int kk = 0; kk < 2; ++kk)
#pragma unroll
            for (int dt = 0; dt < 4; ++dt) {
                int row = dt * 16 + l15;
                int colB = (kk * 64 + (g << 4)) ^ ((row & 7) << 4);
                vf[kk][dt] = *(const bf16x8*)((const char*)Vs[cur] + row * 128 + colB);
            }

        // ---- mask bias (log2 domain): (1-v)*(-C) = fma(v, C, -C)
        float bb[4][4];
#pragma unroll
        for (int kt = 0; kt < 4; ++kt)
#pragma unroll
            for (int r = 0; r < 4; ++r)
                bb[kt][r] = fmaf(vm[kt][r], 1.442695e10f, -1.442695e10f);

        // ---- online softmax per q-subtile; P -> bf16 -> per-wave LDS
#pragma unroll
        for (int qt = 0; qt < 2; ++qt) {
            float s[4][4];
            float tmax = -1e30f;
#pragma unroll
            for (int kt = 0; kt < 4; ++kt)
#pragma unroll
                for (int r = 0; r < 4; ++r) {
                    float val = sc[qt][kt][r] + bb[kt][r];
                    s[kt][r] = val;
                    tmax = fmaxf(tmax, val);
                }
            tmax = fmaxf(tmax, __shfl_xor(tmax, 16));
            tmax = fmaxf(tmax, __shfl_xor(tmax, 32));
            float m = mrow[qt];
            if (!__all(tmax - m <= 8.0f)) {    // defer-max: P bounded by 2^8
                float mnew = fmaxf(m, tmax);
                float al = __builtin_amdgcn_exp2f(m - mnew);
                mrow[qt] = mnew;
                lpart[qt] *= al;
#pragma unroll
                for (int dt = 0; dt < 4; ++dt) accO[qt][dt] *= al;
                m = mnew;
            }
            float lsum = 0.f;
            int prow = qt * 16 + l15;
#pragma unroll
            for (int kt = 0; kt < 4; ++kt) {
                u16x4 pv;
#pragma unroll
                for (int r = 0; r < 4; ++r) {
                    float p = __builtin_amdgcn_exp2f(s[kt][r] - m);
                    lsum += p;
                    pv[r] = f2b(p);
                }
                int colB = (kt * 32 + g * 8) ^ ((l15 & 7) << 4);
                *(u16x4*)((char*)Ps[w] + prow * 128 + colB) = pv;
            }
            lpart[qt] += lsum;
        }

        // COMPILER FENCE: P round-trip is a cross-lane exchange through LDS;
        // force all P stores to be emitted before any P read.
        asm volatile("s_waitcnt lgkmcnt(0)" ::: "memory");

        // ---- O^T += V^T P^T (16 MFMA)
#pragma unroll
        for (int kk = 0; kk < 2; ++kk) {
            bf16x8 pf[2];
#pragma unroll
            for (int qt = 0; qt < 2; ++qt) {
                int prow = qt * 16 + l15;
                int colP = (kk * 64 + (g << 4)) ^ ((l15 & 7) << 4);
                pf[qt] = *(const bf16x8*)((const char*)Ps[w] + prow * 128 + colP);
            }
            __builtin_amdgcn_s_setprio(1);
#pragma unroll
            for (int qt = 0; qt < 2; ++qt)
#pragma unroll
                for (int dt = 0; dt < 4; ++dt)
                    accO[qt][dt] = __builtin_amdgcn_mfma_f32_16x16x32_bf16(
                        vf[kk][dt], pf[qt], accO[qt][dt], 0, 0, 0);
            __builtin_amdgcn_s_setprio(0);
        }
        __syncthreads();
    }

    // ---- epilogue: reduce l across lane groups, apply q_mask, float4 stores
#pragma unroll
    for (int qt = 0; qt < 2; ++qt) {
        float lq = lpart[qt];
        lq += __shfl_xor(lq, 16);
        lq += __shfl_xor(lq, 32);
        int qrow = q0 + qt * 16 + l15;
        float qm = q_mask[(size_t)b * SEQ + qrow];
        float inv = (lq > 0.f) ? qm / lq : 0.f;
#pragma unroll
        for (int dt = 0; dt < 4; ++dt) {
            f32x4 o = accO[qt][dt] * inv;
            *(f32x4*)(&out[((size_t)b * SEQ + qrow) * 768 + h * HD + dt * 16 + g * 4]) = o;
        }
    }
}

extern "C" void kernel_launch(void* const* d_in, const int* in_sizes, int n_in,
                              void* d_out, int out_size, void* d_ws, size_t ws_size,
                              hipStream_t stream) {
    const float* q      = (const float*)d_in[0];
    const float* k      = (const float*)d_in[1];
    const float* v      = (const float*)d_in[2];
    const float* vmask  = (const float*)d_in[3];
    const float* qmask  = (const float*)d_in[4];
    const float* Wq     = (const float*)d_in[5];
    const float* Wk     = (const float*)d_in[6];
    const float* Wv     = (const float*)d_in[7];
    float* out = (float*)d_out;

    u16* Xq  = (u16*)d_ws;
    u16* Xk  = Xq + (size_t)BS * DMODEL;
    u16* Xv  = Xk + (size_t)BS * DMODEL;
    u16* WTq = Xv + (size_t)BS * DMODEL;
    u16* WTk = WTq + (size_t)DMODEL * DMODEL;
    u16* WTv = WTk + (size_t)DMODEL * DMODEL;
    u16* qwp = WTv + (size_t)DMODEL * DMODEL;
    u16* kwp = qwp + (size_t)BATCH * HEADS * SEQ * HD;
    u16* vtp = kwp + (size_t)BATCH * HEADS * SEQ * HD;

    cvt_x<<<dim3(BS * DMODEL / 8 / 256, 1, 3), 256, 0, stream>>>(q, k, v, Xq, Xk, Xv);
    cvt_wt<<<dim3(DMODEL / 32, DMODEL / 32, 3), dim3(32, 8), 0, stream>>>(
        Wq, Wk, Wv, WTq, WTk, WTv);
    proj_gemm<<<dim3(BS / 128, DMODEL / 128, 3), 256, 0, stream>>>(
        Xq, Xk, Xv, WTq, WTk, WTv, qwp, kwp, vtp);
    attn<<<dim3(SEQ / 64, BATCH * HEADS), 128, 0, stream>>>(
        qwp, kwp, vtp, vmask, qmask, out);
}